// Round 12
// baseline (63.957 us; speedup 1.0000x reference)
//
#include <hip/hip_runtime.h>
#include <math.h>

#define B_ 16
#define T_ 12
#define N_ 325
#define C_ 64
#define K_ 8
#define L_ 3900            // N_*T_
#define M_ 249600          // C_*L_
#define M4_ 62400          // M_/4
#define LCH_ 61            // ceil(L_/64)
#define NG_ 8              // n-group size in knorm
#define NGRP_ 41           // ceil(N_/NG_)
#define LOG2PI_ 1.8378770664093453f

// ---------------- workspace layout (floats) ----------------
#define OFF_LOGGAM 0            // 128
#define OFF_PART   128          // 256
#define OFF_CTR    384          // 1 unsigned
#define OFF_MUS    512          // 8192
#define OFF_ISIG   8704         // 8192
#define OFF_T1     16896        // 8192
#define OFF_SPART  25088        // 7808 = 128*61
#define OFF_P      32896        // 499200 = B*K*L
#define OFF_AAUG   532096       // 3993600 = B*C*L
#define OFF_GPART  4525696      // 124800 = 128*975 (transposed)
#define OFF_CONVP  4650496      // 998400 = 61*16384
// total = 5648896 floats = 22.6 MB

// kA: per (b, l-chunk 64): stage raw rep_aug tile, L2-normalize over C in-LDS,
//     write normalized transposed Aaug chunk AND conv partials. (R5-proven)
__global__ __launch_bounds__(256) void kA(const float* __restrict__ rep_aug,
                                          const float* __restrict__ Wmu,
                                          const float* __restrict__ Wsg,
                                          float* __restrict__ Aaug,
                                          float* __restrict__ convp) {
    int b = blockIdx.x / LCH_, lc = blockIdx.x - b * LCH_;
    int l0 = lc * 64;
    __shared__ float ldsA[64 * 65];      // [ll][c]
    __shared__ float sc[64];
    __shared__ float ldsW[16 * 64];
    int tid = threadIdx.x, lane = tid & 63, wv = tid >> 6;
    const float4* r4 = (const float4*)rep_aug;
    for (int i4 = tid; i4 < 1024; i4 += 256) {
        int ll = i4 >> 4, c4 = i4 & 15;
        int l = l0 + ll;
        float4 v = make_float4(0.f, 0.f, 0.f, 0.f);
        if (l < L_) {
            int n = l / T_, t = l - n * T_;
            v = r4[(size_t)((b * T_ + t) * N_ + n) * 16 + c4];
        }
        int base = ll * 65 + c4 * 4;
        ldsA[base] = v.x; ldsA[base+1] = v.y; ldsA[base+2] = v.z; ldsA[base+3] = v.w;
    }
    for (int idx = tid; idx < 1024; idx += 256) {
        int r = idx >> 6, ll = idx & 63;
        int l = l0 + ll;
        float w = 0.0f;
        if (l < L_) w = (r < 8) ? Wmu[r * L_ + l] : Wsg[(r - 8) * L_ + l];
        ldsW[r * 64 + ll] = w;
    }
    __syncthreads();
    #pragma unroll 4
    for (int i = 0; i < 16; ++i) {
        int p = wv * 16 + i;
        float x = ldsA[p * 65 + lane];
        float ss = x * x;
        #pragma unroll
        for (int m = 1; m < 64; m <<= 1) ss += __shfl_xor(ss, m);
        if (lane == 0) sc[p] = 1.0f / fmaxf(sqrtf(ss), 1e-12f);
    }
    __syncthreads();
    // write normalized transposed chunk: 64 consecutive floats per c row
    for (int idx = tid; idx < 4096; idx += 256) {
        int c = idx >> 6, ll = idx & 63;
        int l = l0 + ll;
        if (l < L_)
            Aaug[(size_t)(b * C_ + c) * L_ + l] = ldsA[ll * 65 + c] * sc[ll];
    }
    // conv partials: thread owns (c, 4 k's)
    int c = lane, kk = wv;
    const float* w0 = &ldsW[(kk * 4 + 0) * 64];
    const float* w1 = &ldsW[(kk * 4 + 1) * 64];
    const float* w2 = &ldsW[(kk * 4 + 2) * 64];
    const float* w3 = &ldsW[(kk * 4 + 3) * 64];
    float a0 = 0.f, a1 = 0.f, a2 = 0.f, a3 = 0.f;
    #pragma unroll 8
    for (int l = 0; l < 64; ++l) {
        float a = ldsA[l * 65 + c] * sc[l];
        a0 = fmaf(a, w0[l], a0);
        a1 = fmaf(a, w1[l], a1);
        a2 = fmaf(a, w2[l], a2);
        a3 = fmaf(a, w3[l], a3);
    }
    float* dst = convp + (size_t)lc * 16384 + b * 1024 + c * 16 + kk * 4;
    dst[0] = a0; dst[1] = a1; dst[2] = a2; dst[3] = a3;
}

// kB: gamma logit partials (blocks 0..974, Wg read ONCE, float4 coalesced,
//     contiguous Aaug) + convfin (blocks 975..1038) + ctr reset. (R5-proven)
__global__ __launch_bounds__(256) void kB(const float* __restrict__ Aaug,
                                          const float* __restrict__ Wg,
                                          const float* __restrict__ convp,
                                          const float* __restrict__ bmu,
                                          const float* __restrict__ bsg,
                                          float* __restrict__ gpartT,
                                          float* __restrict__ mus,
                                          float* __restrict__ isig,
                                          float* __restrict__ t1,
                                          unsigned* __restrict__ ctr) {
    int tid = threadIdx.x, lane = tid & 63, wv = tid >> 6;
    if (blockIdx.x < 975) {
        const float4* A4 = (const float4*)Aaug;
        const float4* W4 = (const float4*)Wg;
        int m4 = blockIdx.x * 64 + lane;
        float4 w[K_];
        #pragma unroll
        for (int k = 0; k < K_; ++k) w[k] = W4[(size_t)k * M4_ + m4];
        float acc[4][K_];
        #pragma unroll
        for (int bb = 0; bb < 4; ++bb) {
            float4 a = A4[(size_t)(wv * 4 + bb) * M4_ + m4];
            #pragma unroll
            for (int k = 0; k < K_; ++k)
                acc[bb][k] = a.x * w[k].x + a.y * w[k].y + a.z * w[k].z + a.w * w[k].w;
        }
        __shared__ float red[128];
        #pragma unroll
        for (int bb = 0; bb < 4; ++bb)
            #pragma unroll
            for (int k = 0; k < K_; ++k) {
                float v = acc[bb][k];
                #pragma unroll
                for (int m = 1; m < 64; m <<= 1) v += __shfl_xor(v, m);
                if (lane == 0) red[wv * 32 + bb * 8 + k] = v;
            }
        __syncthreads();
        // red index = b*8+k; write transposed for kC's coalesced reduce
        if (tid < 128) gpartT[(size_t)tid * 975 + blockIdx.x] = red[tid];
    } else {
        if (blockIdx.x == 975 && tid == 0) *ctr = 0u;   // reset kD's counter
        int o = (blockIdx.x - 975) * 256 + tid;     // 0..16383 = b*1024+c*16+kk
        float s = 0.0f;
        #pragma unroll 8
        for (int lc = 0; lc < LCH_; ++lc) s += convp[(size_t)lc * 16384 + o];
        int bc = o >> 4, kk = o & 15, k = kk & 7;
        if (kk < 8) {
            mus[bc * 8 + k] = s + bmu[k];
        } else {
            float logit = s + bsg[k];
            isig[bc * 8 + k] = expf(-logit);
            t1[bc * 8 + k] = -logit - 0.5f * LOG2PI_;
        }
    }
}

// kC: gamma log-softmax (blocks 0..15) + prod (blocks 16..991). (R5-proven)
__global__ __launch_bounds__(256) void kC(const float* __restrict__ rep,
                                          const float* __restrict__ gpartT,
                                          const float* __restrict__ mus,
                                          const float* __restrict__ isig,
                                          const float* __restrict__ t1,
                                          float* __restrict__ loggam,
                                          float* __restrict__ P,
                                          float* __restrict__ Spart) {
    int tid = threadIdx.x, lane = tid & 63, wv = tid >> 6;
    if (blockIdx.x < 16) {
        int b = blockIdx.x;
        int k = tid >> 5, i5 = tid & 31;
        float s = 0.0f;
        for (int i = i5; i < 975; i += 32) s += gpartT[(size_t)(b * 8 + k) * 975 + i];
        #pragma unroll
        for (int m = 1; m < 32; m <<= 1) s += __shfl_xor(s, m);
        __shared__ float red[8];
        if (i5 == 0) red[k] = s;
        __syncthreads();
        if (tid < 8) {
            float mx = -1e30f;
            #pragma unroll
            for (int j = 0; j < 8; ++j) mx = fmaxf(mx, red[j]);
            float sum = 0.0f;
            #pragma unroll
            for (int j = 0; j < 8; ++j) sum += expf(red[j] - mx);
            loggam[b * 8 + tid] = red[tid] - mx - logf(sum);
        }
    } else {
        int j = blockIdx.x - 16;
        int b = j / LCH_, lc = j - b * LCH_;
        int l0 = lc * 64;
        __shared__ float ldsA[64 * 65];
        __shared__ float sc[64];
        __shared__ float ldsMu[512], ldsIs[512], ldsT1[512];
        const float4* r4 = (const float4*)rep;
        for (int i4 = tid; i4 < 1024; i4 += 256) {
            int ll = i4 >> 4, c4 = i4 & 15;
            int l = l0 + ll;
            float4 v = make_float4(0.f, 0.f, 0.f, 0.f);
            if (l < L_) {
                int n = l / T_, t = l - n * T_;
                v = r4[(size_t)((b * T_ + t) * N_ + n) * 16 + c4];
            }
            int base = ll * 65 + c4 * 4;
            ldsA[base] = v.x; ldsA[base+1] = v.y; ldsA[base+2] = v.z; ldsA[base+3] = v.w;
        }
        for (int idx = tid; idx < 512; idx += 256) {
            ldsMu[idx] = mus[b * 512 + idx];
            ldsIs[idx] = isig[b * 512 + idx];
            ldsT1[idx] = t1[b * 512 + idx];
        }
        __syncthreads();
        #pragma unroll 4
        for (int i = 0; i < 16; ++i) {
            int p = wv * 16 + i;
            float x = ldsA[p * 65 + lane];
            float ss = x * x;
            #pragma unroll
            for (int m = 1; m < 64; m <<= 1) ss += __shfl_xor(ss, m);
            if (lane == 0) sc[p] = 1.0f / fmaxf(sqrtf(ss), 1e-12f);
        }
        __syncthreads();
        int l = l0 + lane;
        bool valid = l < L_;
        int k0 = wv * 2, k1i = k0 + 1;
        float scv = sc[lane];
        float p0 = 1.0f, p1 = 1.0f;
        #pragma unroll 8
        for (int c = 0; c < 64; ++c) {
            float a = ldsA[lane * 65 + c] * scv;
            float z0 = (a - ldsMu[c * 8 + k0]) * ldsIs[c * 8 + k0];
            p0 *= ldsT1[c * 8 + k0] - 0.5f * z0 * z0;
            float z1 = (a - ldsMu[c * 8 + k1i]) * ldsIs[c * 8 + k1i];
            p1 *= ldsT1[c * 8 + k1i] - 0.5f * z1 * z1;
        }
        if (!valid) { p0 = 0.0f; p1 = 0.0f; }
        if (valid) {
            P[(size_t)(b * K_ + k0) * L_ + l] = p0;
            P[(size_t)(b * K_ + k1i) * L_ + l] = p1;
        }
        float v0 = p0 * p0, v1 = p1 * p1;
        #pragma unroll
        for (int m = 1; m < 64; m <<= 1) { v0 += __shfl_xor(v0, m); v1 += __shfl_xor(v1, m); }
        if (lane == 0) {
            Spart[(size_t)(b * K_ + k0) * LCH_ + lc] = v0;
            Spart[(size_t)(b * K_ + k1i) * LCH_ + lc] = v1;
        }
    }
}

// kD: per-(b,256-l): invn from Spart, LSE over k, block partial; last of 256
//     blocks reduces all partials deterministically (R8-proven; 256 agent
//     RMWs is the sweet spot — 16-block variant latency-bound (R10),
//     ~1000-RMW variant L2-flush-bound (R9), __threadfence fatal (R7)).
__global__ __launch_bounds__(256) void kD(const float* __restrict__ P,
                                          const float* __restrict__ Spart,
                                          const float* __restrict__ loggam,
                                          float* __restrict__ part,
                                          unsigned* __restrict__ ctr,
                                          float* __restrict__ out) {
    int b = blockIdx.x >> 4, ch = blockIdx.x & 15;
    int tid = threadIdx.x, lane = tid & 63, wv = tid >> 6;
    __shared__ float invk[8], lgk[8];
    if (tid < 8) {
        float s = 0.0f;
        #pragma unroll 8
        for (int i = 0; i < LCH_; ++i) s += Spart[(size_t)(b * 8 + tid) * LCH_ + i];
        invk[tid] = 1.0f / fmaxf(sqrtf(s), 1e-12f);
        lgk[tid] = loggam[b * 8 + tid];
    }
    __syncthreads();
    int l = ch * 256 + tid;
    float ll = 0.0f;
    if (l < L_) {
        float v[K_];
        float mx = -1e30f;
        #pragma unroll
        for (int k = 0; k < K_; ++k) {
            v[k] = P[(size_t)(b * K_ + k) * L_ + l] * invk[k] + lgk[k];
            mx = fmaxf(mx, v[k]);
        }
        float s = 0.0f;
        #pragma unroll
        for (int k = 0; k < K_; ++k) s += expf(v[k] - mx);
        ll = mx + logf(s);
    }
    #pragma unroll
    for (int m = 1; m < 64; m <<= 1) ll += __shfl_xor(ll, m);
    __shared__ float red[4];
    __shared__ bool last;
    if (lane == 0) red[wv] = ll;
    __syncthreads();
    if (tid == 0) {
        float v = red[0] + red[1] + red[2] + red[3];
        __hip_atomic_store(&part[blockIdx.x], v, __ATOMIC_RELEASE, __HIP_MEMORY_SCOPE_AGENT);
        unsigned old = __hip_atomic_fetch_add(ctr, 1u, __ATOMIC_ACQ_REL, __HIP_MEMORY_SCOPE_AGENT);
        last = (old == 255u);
    }
    __syncthreads();
    if (last) {
        float v = __hip_atomic_load(&part[tid], __ATOMIC_ACQUIRE, __HIP_MEMORY_SCOPE_AGENT);
        double d = (double)v;
        #pragma unroll
        for (int m = 1; m < 64; m <<= 1) d += __shfl_xor(d, m);
        __shared__ double dred[4];
        if (lane == 0) dred[wv] = d;
        __syncthreads();
        if (tid == 0)
            out[0] = (float)(-(dred[0] + dred[1] + dred[2] + dred[3]) /
                             ((double)B_ * (double)L_));
    }
}

extern "C" void kernel_launch(void* const* d_in, const int* in_sizes, int n_in,
                              void* d_out, int out_size, void* d_ws, size_t ws_size,
                              hipStream_t stream) {
    const float* rep     = (const float*)d_in[0];
    const float* rep_aug = (const float*)d_in[1];
    const float* Wg      = (const float*)d_in[2];
    const float* Wmu     = (const float*)d_in[3];
    const float* bmu     = (const float*)d_in[4];
    const float* Wsg     = (const float*)d_in[5];
    const float* bsg     = (const float*)d_in[6];
    float* out = (float*)d_out;
    float* ws  = (float*)d_ws;

    float* loggam  = ws + OFF_LOGGAM;
    float* part    = ws + OFF_PART;
    unsigned* ctr  = (unsigned*)(ws + OFF_CTR);
    float* mus     = ws + OFF_MUS;
    float* isig    = ws + OFF_ISIG;
    float* t1      = ws + OFF_T1;
    float* Spart   = ws + OFF_SPART;
    float* P       = ws + OFF_P;
    float* Aaug    = ws + OFF_AAUG;
    float* gpartT  = ws + OFF_GPART;
    float* convp   = ws + OFF_CONVP;

    kA<<<B_ * LCH_, 256, 0, stream>>>(rep_aug, Wmu, Wsg, Aaug, convp);
    kB<<<975 + 64, 256, 0, stream>>>(Aaug, Wg, convp, bmu, bsg, gpartT, mus, isig, t1, ctr);
    kC<<<16 + B_ * LCH_, 256, 0, stream>>>(rep, gpartT, mus, isig, t1, loggam, P, Spart);
    kD<<<B_ * 16, 256, 0, stream>>>(P, Spart, loggam, part, ctr, out);
}

// Round 13
// 62.725 us; speedup vs baseline: 1.0196x; 1.0196x over previous
//
#include <hip/hip_runtime.h>
#include <math.h>

#define B_ 16
#define T_ 12
#define N_ 325
#define C_ 64
#define K_ 8
#define L_ 3900            // N_*T_
#define M_ 249600          // C_*L_
#define M4_ 62400          // M_/4
#define LCH_ 61            // ceil(L_/64)
#define LOG2PI_ 1.8378770664093453f

// ---------------- workspace layout (floats) ----------------
#define OFF_LOGGAM 0            // 128
#define OFF_PART   128          // 256
#define OFF_CTR    384          // 1 unsigned
#define OFF_MUS    512          // 8192  [b][k][c] transposed
#define OFF_ISIG   8704         // 8192  [b][k][c]
#define OFF_T1     16896        // 8192  [b][k][c]
#define OFF_SPART  25088        // 7808 = 128*61
#define OFF_P      32896        // 499200 = B*K*L
#define OFF_AAUG   532096       // 3993600 = B*C*L
#define OFF_GPART  4525696      // 124800 = 128*975 (transposed)
#define OFF_CONVP  4650496      // 998400 = 61*16384
// total = 5648896 floats = 22.6 MB

// kA: per (b, l-chunk 64): stage raw rep_aug tile, L2-normalize over C in-LDS
//     (in-place), write transposed Aaug chunk AND conv partials.
//     Conv weights read via wave-uniform (readfirstlane) addresses -> s_load
//     on the SMEM pipe; hot loop has ONE ds_read per iteration.
__global__ __launch_bounds__(256) void kA(const float* __restrict__ rep_aug,
                                          const float* __restrict__ Wmu,
                                          const float* __restrict__ Wsg,
                                          float* __restrict__ Aaug,
                                          float* __restrict__ convp) {
    int b = blockIdx.x / LCH_, lc = blockIdx.x - b * LCH_;
    int l0 = lc * 64;
    __shared__ float ldsA[64 * 65];      // [ll][c]
    __shared__ float sc[64];
    int tid = threadIdx.x, lane = tid & 63, wv = tid >> 6;
    const float4* r4 = (const float4*)rep_aug;
    for (int i4 = tid; i4 < 1024; i4 += 256) {
        int ll = i4 >> 4, c4 = i4 & 15;
        int l = l0 + ll;
        float4 v = make_float4(0.f, 0.f, 0.f, 0.f);
        if (l < L_) {
            int n = l / T_, t = l - n * T_;
            v = r4[(size_t)((b * T_ + t) * N_ + n) * 16 + c4];
        }
        int base = ll * 65 + c4 * 4;
        ldsA[base] = v.x; ldsA[base+1] = v.y; ldsA[base+2] = v.z; ldsA[base+3] = v.w;
    }
    __syncthreads();
    #pragma unroll 4
    for (int i = 0; i < 16; ++i) {
        int p = wv * 16 + i;
        float x = ldsA[p * 65 + lane];
        float ss = x * x;
        #pragma unroll
        for (int m = 1; m < 64; m <<= 1) ss += __shfl_xor(ss, m);
        if (lane == 0) sc[p] = 1.0f / fmaxf(sqrtf(ss), 1e-12f);
    }
    __syncthreads();
    // normalize in place (so conv loop + Aaug write need no per-iter scale)
    for (int idx = tid; idx < 4096; idx += 256) {
        int r = idx >> 6, cc = idx & 63;
        ldsA[r * 65 + cc] *= sc[r];
    }
    __syncthreads();
    // write normalized transposed chunk: 64 consecutive floats per c row
    for (int idx = tid; idx < 4096; idx += 256) {
        int c = idx >> 6, ll = idx & 63;
        int l = l0 + ll;
        if (l < L_)
            Aaug[(size_t)(b * C_ + c) * L_ + l] = ldsA[ll * 65 + c];
    }
    // conv partials: c = lane; wave handles 4 k-rows via scalar-loaded weights
    int wvu = __builtin_amdgcn_readfirstlane(wv);
    const float* wb = (wvu < 2) ? Wmu : Wsg;
    const float* pw = wb + (size_t)((wvu & 1) * 4) * L_ + l0;  // rows r..r+3
    int nl = L_ - l0; if (nl > 64) nl = 64;
    int c = lane;
    float a0 = 0.f, a1 = 0.f, a2 = 0.f, a3 = 0.f;
    #pragma unroll 4
    for (int l = 0; l < nl; ++l) {
        float a = ldsA[l * 65 + c];
        a0 = fmaf(a, pw[l], a0);
        a1 = fmaf(a, pw[L_ + l], a1);
        a2 = fmaf(a, pw[2 * L_ + l], a2);
        a3 = fmaf(a, pw[3 * L_ + l], a3);
    }
    float* dst = convp + (size_t)lc * 16384 + b * 1024 + c * 16 + wvu * 4;
    dst[0] = a0; dst[1] = a1; dst[2] = a2; dst[3] = a3;
}

// kB: gamma logit partials (blocks 0..974, Wg read ONCE, float4 coalesced,
//     contiguous Aaug) + convfin (blocks 975..1038, writes [b][k][c]
//     transposed params) + ctr reset.
__global__ __launch_bounds__(256) void kB(const float* __restrict__ Aaug,
                                          const float* __restrict__ Wg,
                                          const float* __restrict__ convp,
                                          const float* __restrict__ bmu,
                                          const float* __restrict__ bsg,
                                          float* __restrict__ gpartT,
                                          float* __restrict__ muT,
                                          float* __restrict__ isT,
                                          float* __restrict__ t1T,
                                          unsigned* __restrict__ ctr) {
    int tid = threadIdx.x, lane = tid & 63, wv = tid >> 6;
    if (blockIdx.x < 975) {
        const float4* A4 = (const float4*)Aaug;
        const float4* W4 = (const float4*)Wg;
        int m4 = blockIdx.x * 64 + lane;
        float4 w[K_];
        #pragma unroll
        for (int k = 0; k < K_; ++k) w[k] = W4[(size_t)k * M4_ + m4];
        float acc[4][K_];
        #pragma unroll
        for (int bb = 0; bb < 4; ++bb) {
            float4 a = A4[(size_t)(wv * 4 + bb) * M4_ + m4];
            #pragma unroll
            for (int k = 0; k < K_; ++k)
                acc[bb][k] = a.x * w[k].x + a.y * w[k].y + a.z * w[k].z + a.w * w[k].w;
        }
        __shared__ float red[128];
        #pragma unroll
        for (int bb = 0; bb < 4; ++bb)
            #pragma unroll
            for (int k = 0; k < K_; ++k) {
                float v = acc[bb][k];
                #pragma unroll
                for (int m = 1; m < 64; m <<= 1) v += __shfl_xor(v, m);
                if (lane == 0) red[wv * 32 + bb * 8 + k] = v;
            }
        __syncthreads();
        if (tid < 128) gpartT[(size_t)tid * 975 + blockIdx.x] = red[tid];
    } else {
        if (blockIdx.x == 975 && tid == 0) *ctr = 0u;   // reset kD's counter
        int o = (blockIdx.x - 975) * 256 + tid;     // 0..16383 = b*1024+c*16+kk
        float s = 0.0f;
        #pragma unroll 8
        for (int lc = 0; lc < LCH_; ++lc) s += convp[(size_t)lc * 16384 + o];
        int bc = o >> 4, kk = o & 15, k = kk & 7;
        int b = bc >> 6, c = bc & 63;
        int oT = b * 512 + k * 64 + c;              // [b][k][c]
        if (kk < 8) {
            muT[oT] = s + bmu[k];
        } else {
            float logit = s + bsg[k];
            isT[oT] = expf(-logit);
            t1T[oT] = -logit - 0.5f * LOG2PI_;
        }
    }
}

// kC: gamma log-softmax (blocks 0..15) + prod (blocks 16..991).
//     Product loop reads params via wave-uniform addresses (readfirstlane'd
//     k) from [b][k][c]-transposed arrays -> batched s_load on SMEM pipe;
//     ONE ds_read per iteration (was 7).
__global__ __launch_bounds__(256) void kC(const float* __restrict__ rep,
                                          const float* __restrict__ gpartT,
                                          const float* __restrict__ muT,
                                          const float* __restrict__ isT,
                                          const float* __restrict__ t1T,
                                          float* __restrict__ loggam,
                                          float* __restrict__ P,
                                          float* __restrict__ Spart) {
    int tid = threadIdx.x, lane = tid & 63, wv = tid >> 6;
    if (blockIdx.x < 16) {
        int b = blockIdx.x;
        int k = tid >> 5, i5 = tid & 31;
        float s = 0.0f;
        for (int i = i5; i < 975; i += 32) s += gpartT[(size_t)(b * 8 + k) * 975 + i];
        #pragma unroll
        for (int m = 1; m < 32; m <<= 1) s += __shfl_xor(s, m);
        __shared__ float red[8];
        if (i5 == 0) red[k] = s;
        __syncthreads();
        if (tid < 8) {
            float mx = -1e30f;
            #pragma unroll
            for (int j = 0; j < 8; ++j) mx = fmaxf(mx, red[j]);
            float sum = 0.0f;
            #pragma unroll
            for (int j = 0; j < 8; ++j) sum += expf(red[j] - mx);
            loggam[b * 8 + tid] = red[tid] - mx - logf(sum);
        }
    } else {
        int j = blockIdx.x - 16;
        int b = j / LCH_, lc = j - b * LCH_;
        int l0 = lc * 64;
        __shared__ float ldsA[64 * 65];
        __shared__ float sc[64];
        const float4* r4 = (const float4*)rep;
        for (int i4 = tid; i4 < 1024; i4 += 256) {
            int ll = i4 >> 4, c4 = i4 & 15;
            int l = l0 + ll;
            float4 v = make_float4(0.f, 0.f, 0.f, 0.f);
            if (l < L_) {
                int n = l / T_, t = l - n * T_;
                v = r4[(size_t)((b * T_ + t) * N_ + n) * 16 + c4];
            }
            int base = ll * 65 + c4 * 4;
            ldsA[base] = v.x; ldsA[base+1] = v.y; ldsA[base+2] = v.z; ldsA[base+3] = v.w;
        }
        __syncthreads();
        #pragma unroll 4
        for (int i = 0; i < 16; ++i) {
            int p = wv * 16 + i;
            float x = ldsA[p * 65 + lane];
            float ss = x * x;
            #pragma unroll
            for (int m = 1; m < 64; m <<= 1) ss += __shfl_xor(ss, m);
            if (lane == 0) sc[p] = 1.0f / fmaxf(sqrtf(ss), 1e-12f);
        }
        __syncthreads();
        int l = l0 + lane;
        bool valid = l < L_;
        int wvu = __builtin_amdgcn_readfirstlane(wv);
        int k0 = wvu * 2, k1i = k0 + 1;
        const float* mu0 = muT + b * 512 + k0 * 64;
        const float* mu1 = muT + b * 512 + k1i * 64;
        const float* is0 = isT + b * 512 + k0 * 64;
        const float* is1 = isT + b * 512 + k1i * 64;
        const float* tt0 = t1T + b * 512 + k0 * 64;
        const float* tt1 = t1T + b * 512 + k1i * 64;
        float scv = sc[lane];
        float p0 = 1.0f, p1 = 1.0f;
        #pragma unroll 8
        for (int c = 0; c < 64; ++c) {
            float a = ldsA[lane * 65 + c] * scv;
            float z0 = (a - mu0[c]) * is0[c];
            p0 *= tt0[c] - 0.5f * z0 * z0;
            float z1 = (a - mu1[c]) * is1[c];
            p1 *= tt1[c] - 0.5f * z1 * z1;
        }
        if (!valid) { p0 = 0.0f; p1 = 0.0f; }
        if (valid) {
            P[(size_t)(b * K_ + k0) * L_ + l] = p0;
            P[(size_t)(b * K_ + k1i) * L_ + l] = p1;
        }
        float v0 = p0 * p0, v1 = p1 * p1;
        #pragma unroll
        for (int m = 1; m < 64; m <<= 1) { v0 += __shfl_xor(v0, m); v1 += __shfl_xor(v1, m); }
        if (lane == 0) {
            Spart[(size_t)(b * K_ + k0) * LCH_ + lc] = v0;
            Spart[(size_t)(b * K_ + k1i) * LCH_ + lc] = v1;
        }
    }
}

// kD: per-(b,256-l): invn from Spart, LSE over k, block partial; last of 256
//     blocks reduces all partials deterministically (R8/R12-proven; 256 agent
//     RMWs is the sweet spot — 16-block variant latency-bound (R10),
//     ~1000-RMW variant L2-flush-bound (R9), __threadfence fatal (R7)).
__global__ __launch_bounds__(256) void kD(const float* __restrict__ P,
                                          const float* __restrict__ Spart,
                                          const float* __restrict__ loggam,
                                          float* __restrict__ part,
                                          unsigned* __restrict__ ctr,
                                          float* __restrict__ out) {
    int b = blockIdx.x >> 4, ch = blockIdx.x & 15;
    int tid = threadIdx.x, lane = tid & 63, wv = tid >> 6;
    __shared__ float invk[8], lgk[8];
    if (tid < 8) {
        float s = 0.0f;
        #pragma unroll 8
        for (int i = 0; i < LCH_; ++i) s += Spart[(size_t)(b * 8 + tid) * LCH_ + i];
        invk[tid] = 1.0f / fmaxf(sqrtf(s), 1e-12f);
        lgk[tid] = loggam[b * 8 + tid];
    }
    __syncthreads();
    int l = ch * 256 + tid;
    float ll = 0.0f;
    if (l < L_) {
        float v[K_];
        float mx = -1e30f;
        #pragma unroll
        for (int k = 0; k < K_; ++k) {
            v[k] = P[(size_t)(b * K_ + k) * L_ + l] * invk[k] + lgk[k];
            mx = fmaxf(mx, v[k]);
        }
        float s = 0.0f;
        #pragma unroll
        for (int k = 0; k < K_; ++k) s += expf(v[k] - mx);
        ll = mx + logf(s);
    }
    #pragma unroll
    for (int m = 1; m < 64; m <<= 1) ll += __shfl_xor(ll, m);
    __shared__ float red[4];
    __shared__ bool last;
    if (lane == 0) red[wv] = ll;
    __syncthreads();
    if (tid == 0) {
        float v = red[0] + red[1] + red[2] + red[3];
        __hip_atomic_store(&part[blockIdx.x], v, __ATOMIC_RELEASE, __HIP_MEMORY_SCOPE_AGENT);
        unsigned old = __hip_atomic_fetch_add(ctr, 1u, __ATOMIC_ACQ_REL, __HIP_MEMORY_SCOPE_AGENT);
        last = (old == 255u);
    }
    __syncthreads();
    if (last) {
        float v = __hip_atomic_load(&part[tid], __ATOMIC_ACQUIRE, __HIP_MEMORY_SCOPE_AGENT);
        double d = (double)v;
        #pragma unroll
        for (int m = 1; m < 64; m <<= 1) d += __shfl_xor(d, m);
        __shared__ double dred[4];
        if (lane == 0) dred[wv] = d;
        __syncthreads();
        if (tid == 0)
            out[0] = (float)(-(dred[0] + dred[1] + dred[2] + dred[3]) /
                             ((double)B_ * (double)L_));
    }
}

extern "C" void kernel_launch(void* const* d_in, const int* in_sizes, int n_in,
                              void* d_out, int out_size, void* d_ws, size_t ws_size,
                              hipStream_t stream) {
    const float* rep     = (const float*)d_in[0];
    const float* rep_aug = (const float*)d_in[1];
    const float* Wg      = (const float*)d_in[2];
    const float* Wmu     = (const float*)d_in[3];
    const float* bmu     = (const float*)d_in[4];
    const float* Wsg     = (const float*)d_in[5];
    const float* bsg     = (const float*)d_in[6];
    float* out = (float*)d_out;
    float* ws  = (float*)d_ws;

    float* loggam  = ws + OFF_LOGGAM;
    float* part    = ws + OFF_PART;
    unsigned* ctr  = (unsigned*)(ws + OFF_CTR);
    float* muT     = ws + OFF_MUS;
    float* isT     = ws + OFF_ISIG;
    float* t1T     = ws + OFF_T1;
    float* Spart   = ws + OFF_SPART;
    float* P       = ws + OFF_P;
    float* Aaug    = ws + OFF_AAUG;
    float* gpartT  = ws + OFF_GPART;
    float* convp   = ws + OFF_CONVP;

    kA<<<B_ * LCH_, 256, 0, stream>>>(rep_aug, Wmu, Wsg, Aaug, convp);
    kB<<<975 + 64, 256, 0, stream>>>(Aaug, Wg, convp, bmu, bsg, gpartT, muT, isT, t1T, ctr);
    kC<<<16 + B_ * LCH_, 256, 0, stream>>>(rep, gpartT, muT, isT, t1T, loggam, P, Spart);
    kD<<<B_ * 16, 256, 0, stream>>>(P, Spart, loggam, part, ctr, out);
}